// Round 3
// baseline (373.446 us; speedup 1.0000x reference)
//
#include <hip/hip_runtime.h>
#include <math.h>

#define NIMG 8
#define NCLS 80
#define HH 200
#define WW 200
#define HW (HH*WW)          // 40000
#define M (NCLS*HW)         // 3,200,000 entries per image
#define NBINS 8192
#define BIN_SHIFT 18        // top 14 bits of positive float
#define CAND_MAX 4096
#define TOPK 1000
#define OUTK 100
#define PRE_T 0.05f
#define PRE_T_LOOSE 0.0499f
#define NMS_T 0.6f
#define L2E 1.44269504f

#define GX1 32              // blocks/image for k1 (1024 thr, 32KB LDS hist)
#define TILE1 (1024*16)     // 16384 floats per tile
#define NT1 ((M + TILE1 - 1)/TILE1)   // 196
#define GX3 64              // blocks/image for k3 (512 thr)
#define TILE3 (512*16)      // 8192
#define NT3 ((M + TILE3 - 1)/TILE3)   // 391

// device-global scratch (no ws dependence)
__device__ unsigned int       g_part[NIMG][GX1][NBINS];  // per-block partial hists (8MB)
__device__ unsigned int       g_cnt[NIMG];
__device__ int                g_ccut[NIMG];   // collect cut (rawcut-2, clamped)
__device__ int                g_rcut[NIMG];   // rank cut    (rawcut-1)
__device__ float              g_sct[NIMG * HW];
__device__ unsigned long long g_cand[NIMG][CAND_MAX];
__device__ unsigned long long g_top[NIMG][1024];

__device__ __forceinline__ float sigmoid_exact(float x){
    return 1.0f / (1.0f + expf(-x));      // bit-matches ref (r1/r2: absmax 0)
}
__device__ __forceinline__ float sigmoid_fast(float x){
    return __builtin_amdgcn_rcpf(1.0f + __builtin_amdgcn_exp2f(-x * L2E));
}

__global__ void k0_init(const float* __restrict__ cent){
    int t = blockIdx.x * blockDim.x + threadIdx.x;
    int stride = gridDim.x * blockDim.x;
    if (t < NIMG) g_cnt[t] = 0u;
    for (int i = t; i < NIMG * HW; i += stride)
        g_sct[i] = sigmoid_exact(cent[i]);
}

// Pass 1: per-image histogram of APPROX score bits.
// Loads batched: 4x cls float4 + 4x sct float4 issued before any branchy compute.
__global__ void __launch_bounds__(1024) k1_hist(const float* __restrict__ cls){
    int n = blockIdx.y;
    __shared__ unsigned int sh[NBINS];
    for (int i = threadIdx.x; i < NBINS; i += 1024) sh[i] = 0u;
    __syncthreads();
    const float* cls_n = cls + (size_t)n * M;
    const float* sct_n = g_sct + n * HW;
    for (int tile = blockIdx.x; tile < NT1; tile += GX1){
        int e0 = tile * TILE1 + threadIdx.x * 4;
        float4 xv0, xv1, xv2, xv3, cv0, cv1, cv2, cv3;
        int ea0, ea1, ea2, ea3;
        {   // batch all 8 loads up front (kept out of branches -> stays pipelined)
            int e;
            e = e0;            ea0 = e; e = e < M ? e : (M-4); xv0 = *(const float4*)(cls_n + e); cv0 = *(const float4*)(sct_n + (e % HW));
            e = e0 + 4096;     ea1 = e; e = e < M ? e : (M-4); xv1 = *(const float4*)(cls_n + e); cv1 = *(const float4*)(sct_n + (e % HW));
            e = e0 + 8192;     ea2 = e; e = e < M ? e : (M-4); xv2 = *(const float4*)(cls_n + e); cv2 = *(const float4*)(sct_n + (e % HW));
            e = e0 + 12288;    ea3 = e; e = e < M ? e : (M-4); xv3 = *(const float4*)(cls_n + e); cv3 = *(const float4*)(sct_n + (e % HW));
        }
        #pragma unroll
        for (int k = 0; k < 4; ++k){
            float4 xv = k==0?xv0:k==1?xv1:k==2?xv2:xv3;
            float4 cv = k==0?cv0:k==1?cv1:k==2?cv2:cv3;
            bool ok  = (k==0?ea0:k==1?ea1:k==2?ea2:ea3) < M;
            float xs[4] = {xv.x, xv.y, xv.z, xv.w};
            float cs[4] = {cv.x, cv.y, cv.z, cv.w};
            #pragma unroll
            for (int j = 0; j < 4; ++j){
                float pa = sigmoid_fast(xs[j]);
                if (ok && pa > PRE_T_LOOSE){
                    unsigned int b = __float_as_uint(pa * cs[j]) >> BIN_SHIFT;
                    atomicAdd(&sh[b], 1u);
                }
            }
        }
    }
    __syncthreads();
    uint4* dst = (uint4*)g_part[n][blockIdx.x];
    const uint4* src = (const uint4*)sh;
    for (int i = threadIdx.x; i < NBINS/4; i += 1024) dst[i] = src[i];
}

// Pass 2: sum partial hists, find rawcut (suffix>=TOPK), derive collect/rank cuts
__global__ void __launch_bounds__(1024) k2_cut(){
    int n = blockIdx.x;
    __shared__ unsigned int hist[NBINS];
    __shared__ unsigned int csum[256];
    for (int b = threadIdx.x; b < NBINS; b += 1024){
        unsigned int s = 0;
        #pragma unroll 4
        for (int j = 0; j < GX1; ++j) s += g_part[n][j][b];
        hist[b] = s;
    }
    __syncthreads();
    if (threadIdx.x < 256){
        unsigned int s = 0;
        int base = threadIdx.x * 32;
        for (int i = 0; i < 32; ++i) s += hist[base + i];
        csum[threadIdx.x] = s;
    }
    __syncthreads();
    if (threadIdx.x == 0){
        unsigned int acc = 0;
        int rawcut = 0;
        int c = 255;
        for (; c >= 0; --c){
            if (acc + csum[c] >= TOPK) break;
            acc += csum[c];
        }
        if (c >= 0){
            int b = c * 32 + 31;
            for (;; --b){
                acc += hist[b];
                if (acc >= TOPK || b == c * 32) break;
            }
            rawcut = b;
        }
        // collect cut: rawcut-2 (1 bin approx-vs-exact margin + 1 bin rank margin)
        int ccut = rawcut;
        unsigned int cnt = acc;
        for (int m = 0; m < 2 && ccut > 0; ++m){ ccut--; cnt += hist[ccut]; }
        while (cnt > CAND_MAX && ccut < NBINS){ cnt -= hist[ccut]; ccut++; }
        int rcut = rawcut > 0 ? rawcut - 1 : 0;
        if (rcut < ccut) rcut = ccut;
        g_ccut[n] = ccut;
        g_rcut[n] = rcut;
    }
}

// Pass 3: re-stream cls (likely L3-warm), approx-screen vs ccut, store EXACT keys
__global__ void __launch_bounds__(512) k3_collect(const float* __restrict__ cls){
    int n = blockIdx.y;
    unsigned int ccut = (unsigned int)g_ccut[n];
    const float* cls_n = cls + (size_t)n * M;
    const float* sct_n = g_sct + n * HW;
    for (int tile = blockIdx.x; tile < NT3; tile += GX3){
        int e0 = tile * TILE3 + threadIdx.x * 4;
        float4 xv0, xv1, xv2, xv3, cv0, cv1, cv2, cv3;
        int ea0, ea1, ea2, ea3, eh0, eh1, eh2, eh3;
        {
            int e, h;
            e = e0;          ea0 = e; e = e < M ? e : (M-4); h = e % HW; eh0 = h; xv0 = *(const float4*)(cls_n + e); cv0 = *(const float4*)(sct_n + h);
            e = e0 + 2048;   ea1 = e; e = e < M ? e : (M-4); h = e % HW; eh1 = h; xv1 = *(const float4*)(cls_n + e); cv1 = *(const float4*)(sct_n + h);
            e = e0 + 4096;   ea2 = e; e = e < M ? e : (M-4); h = e % HW; eh2 = h; xv2 = *(const float4*)(cls_n + e); cv2 = *(const float4*)(sct_n + h);
            e = e0 + 6144;   ea3 = e; e = e < M ? e : (M-4); h = e % HW; eh3 = h; xv3 = *(const float4*)(cls_n + e); cv3 = *(const float4*)(sct_n + h);
        }
        #pragma unroll
        for (int k = 0; k < 4; ++k){
            float4 xv = k==0?xv0:k==1?xv1:k==2?xv2:xv3;
            float4 cv = k==0?cv0:k==1?cv1:k==2?cv2:cv3;
            int ea    = k==0?ea0:k==1?ea1:k==2?ea2:ea3;
            int hw0   = k==0?eh0:k==1?eh1:k==2?eh2:eh3;
            bool ok = ea < M;
            float xs[4] = {xv.x, xv.y, xv.z, xv.w};
            float cs[4] = {cv.x, cv.y, cv.z, cv.w};
            #pragma unroll
            for (int j = 0; j < 4; ++j){
                float pa = sigmoid_fast(xs[j]);
                if (ok && pa > PRE_T_LOOSE){
                    float sa = pa * cs[j];
                    if ((__float_as_uint(sa) >> BIN_SHIFT) >= ccut){
                        float p = sigmoid_exact(xs[j]);
                        if (p > PRE_T){
                            float sx = p * cs[j];
                            unsigned int bits = __float_as_uint(sx);
                            unsigned int pos = atomicAdd(&g_cnt[n], 1u);
                            if (pos < CAND_MAX){
                                int c  = ea / HW;
                                int hw = hw0 + j;
                                unsigned int idx = (unsigned int)(hw * NCLS + c);
                                g_cand[n][pos] = ((unsigned long long)bits << 32)
                                               | (unsigned long long)(0xFFFFFFFFu - idx);
                            }
                        }
                    }
                }
            }
        }
    }
}

// Pass 4: filter exact-bin >= rcut, rank-select top-1000
__global__ void __launch_bounds__(1024) k4_select(){
    int n = blockIdx.x;
    __shared__ unsigned long long keys[CAND_MAX];
    __shared__ unsigned int lcnt;
    if (threadIdx.x == 0) lcnt = 0;
    g_top[n][threadIdx.x] = 0ull;
    __syncthreads();
    unsigned int cc = g_cnt[n];
    if (cc > CAND_MAX) cc = CAND_MAX;
    unsigned int rcut = (unsigned int)g_rcut[n];
    for (unsigned int i = threadIdx.x; i < cc; i += 1024){
        unsigned long long k = g_cand[n][i];
        if ((unsigned int)(k >> (32 + BIN_SHIFT)) >= rcut){
            unsigned int p = atomicAdd(&lcnt, 1u);
            if (p < CAND_MAX) keys[p] = k;
        }
    }
    __syncthreads();
    int C = (int)(lcnt < CAND_MAX ? lcnt : CAND_MAX);
    for (int i = threadIdx.x; i < C; i += 1024){
        unsigned long long k = keys[i];
        int rank = 0;
        for (int j = 0; j < C; ++j) rank += (keys[j] > k) ? 1 : 0;
        if (rank < TOPK) g_top[n][rank] = k;
    }
}

// Pass 5: decode boxes, greedy NMS with early stop at 100 keeps, write output
__global__ void __launch_bounds__(1024) k5_nms(const float* __restrict__ loc,
                                               const float* __restrict__ reg,
                                               const int*   __restrict__ imsz,
                                               float* __restrict__ out){
    int n = blockIdx.x;
    int t = threadIdx.x;
    __shared__ float ox1[TOPK], oy1[TOPK], ox2[TOPK], oy2[TOPK], oar[TOPK];
    __shared__ float bx[TOPK][4];
    __shared__ float sc[TOPK];
    __shared__ int   lab[TOPK];
    __shared__ unsigned char validf[TOPK];
    __shared__ unsigned char supp[TOPK];
    __shared__ int keeplist[OUTK];

    if (t < TOPK){
        unsigned long long k = g_top[n][t];
        unsigned int bits = (unsigned int)(k >> 32);
        float s = __uint_as_float(bits);
        supp[t] = 0;
        if (s > 0.0f){
            unsigned int idx = 0xFFFFFFFFu - (unsigned int)(k & 0xFFFFFFFFull);
            int hw = (int)(idx / NCLS);
            int c  = (int)(idx % NCLS);
            int l  = c + 1;
            float x  = loc[2*hw], y = loc[2*hw + 1];
            float r0 = reg[((size_t)n*4 + 0)*HW + hw];
            float r1 = reg[((size_t)n*4 + 1)*HW + hw];
            float r2 = reg[((size_t)n*4 + 2)*HW + hw];
            float r3 = reg[((size_t)n*4 + 3)*HW + hw];
            float ihh = (float)imsz[2*n + 0];
            float iww = (float)imsz[2*n + 1];
            float x1 = fminf(fmaxf(x - r0, 0.0f), iww - 1.0f);
            float y1 = fminf(fmaxf(y - r1, 0.0f), ihh - 1.0f);
            float x2 = fminf(fmaxf(x + r2, 0.0f), iww - 1.0f);
            float y2 = fminf(fmaxf(y + r3, 0.0f), ihh - 1.0f);
            bx[t][0] = x1; bx[t][1] = y1; bx[t][2] = x2; bx[t][3] = y2;
            float off = (float)l * 100000.0f;   // fp32, as reference (quantizes!)
            float a1 = x1 + off, b1 = y1 + off, a2 = x2 + off, b2 = y2 + off;
            ox1[t] = a1; oy1[t] = b1; ox2[t] = a2; oy2[t] = b2;
            oar[t] = (a2 - a1 + 1.0f) * (b2 - b1 + 1.0f);
            sc[t] = s; lab[t] = l; validf[t] = 1;
        } else {
            validf[t] = 0; sc[t] = 0.0f; lab[t] = 0;
            bx[t][0] = bx[t][1] = bx[t][2] = bx[t][3] = 0.0f;
            ox1[t] = oy1[t] = 0.0f; ox2[t] = oy2[t] = -1.0f; oar[t] = 1.0f;
        }
    }
    __syncthreads();

    int cnt = 0;
    for (int i = 0; i < TOPK; ++i){
        bool keep_i = validf[i] && !supp[i];
        if (keep_i){
            if (t == 0) keeplist[cnt] = i;
            if (t < TOPK && t != i){
                float ix1 = fmaxf(ox1[i], ox1[t]);
                float iy1 = fmaxf(oy1[i], oy1[t]);
                float ix2 = fminf(ox2[i], ox2[t]);
                float iy2 = fminf(oy2[i], oy2[t]);
                float iw_ = fmaxf(ix2 - ix1 + 1.0f, 0.0f);
                float ih_ = fmaxf(iy2 - iy1 + 1.0f, 0.0f);
                float inter = iw_ * ih_;
                float iou = inter / (oar[i] + oar[t] - inter);
                if (iou > NMS_T) supp[t] = 1;
            }
            cnt++;
            __syncthreads();
            if (cnt == OUTK) break;
        }
    }
    __syncthreads();

    if (t < OUTK){
        float r0=0.f,r1=0.f,r2=0.f,r3=0.f,r4=0.f,r5=0.f;
        if (t < cnt){
            int i = keeplist[t];
            r0 = bx[i][0]; r1 = bx[i][1]; r2 = bx[i][2]; r3 = bx[i][3];
            r4 = sqrtf(sc[i]); r5 = (float)lab[i];
        }
        float* o = out + ((size_t)n*OUTK + t)*6;
        o[0]=r0; o[1]=r1; o[2]=r2; o[3]=r3; o[4]=r4; o[5]=r5;
    }
}

extern "C" void kernel_launch(void* const* d_in, const int* in_sizes, int n_in,
                              void* d_out, int out_size, void* d_ws, size_t ws_size,
                              hipStream_t stream){
    const float* loc  = (const float*)d_in[0];
    const float* cls  = (const float*)d_in[1];
    const float* reg  = (const float*)d_in[2];
    const float* cent = (const float*)d_in[3];
    const int*   imsz = (const int*)d_in[4];
    float* out = (float*)d_out;

    hipLaunchKernelGGL(k0_init,    dim3(640),       dim3(512),  0, stream, cent);
    hipLaunchKernelGGL(k1_hist,    dim3(GX1, NIMG), dim3(1024), 0, stream, cls);
    hipLaunchKernelGGL(k2_cut,     dim3(NIMG),      dim3(1024), 0, stream);
    hipLaunchKernelGGL(k3_collect, dim3(GX3, NIMG), dim3(512),  0, stream, cls);
    hipLaunchKernelGGL(k4_select,  dim3(NIMG),      dim3(1024), 0, stream);
    hipLaunchKernelGGL(k5_nms,     dim3(NIMG),      dim3(1024), 0, stream,
                       loc, reg, imsz, out);
}